// Round 2
// baseline (734.460 us; speedup 1.0000x reference)
//
#include <hip/hip_runtime.h>
#include <hip/hip_bf16.h>

typedef unsigned short u16;
typedef __bf16 bf16_t;
typedef bf16_t bf16x8 __attribute__((ext_vector_type(8)));
typedef float f32x4 __attribute__((ext_vector_type(4)));

#define T_TOK 4096
#define DIM   1024
#define NEXP  8
#define HID   2816
#define CAP   8
#define CAPL  3

static __device__ __forceinline__ u16 f2b(float f) {
    __hip_bfloat16 h = __float2bfloat16(f);
    return *(u16*)&h;
}

// async global->LDS: HW writes lane i's 16B at (wave-uniform base)+i*16
static __device__ __forceinline__ void glds16(const u16* g, u16* l) {
    __builtin_amdgcn_global_load_lds((const __attribute__((address_space(1))) void*)g,
                                     (__attribute__((address_space(3))) void*)l, 16, 0, 0);
}

// ---------------- gating (+ fused fp32->bf16 X cast) -----------------------------
__global__ void k_gating(const float* __restrict__ X,
                         const float* __restrict__ WG,
                         int* __restrict__ cnt,
                         int* __restrict__ tok,
                         float* __restrict__ wt,
                         u16* __restrict__ Xbf)
{
    int wv   = threadIdx.x >> 6;
    int lane = threadIdx.x & 63;
    int t = blockIdx.x * 4 + wv;
    float l[NEXP];
#pragma unroll
    for (int e = 0; e < NEXP; ++e) l[e] = 0.f;
#pragma unroll
    for (int i = 0; i < DIM/64; ++i) {
        int d = i*64 + lane;
        float xv = X[(size_t)t*DIM + d];
        Xbf[(size_t)t*DIM + d] = f2b(xv);
        const float* wrow = WG + (size_t)d*NEXP;
        float4 wa = *(const float4*)wrow;
        float4 wb = *(const float4*)(wrow + 4);
        l[0] += xv*wa.x; l[1] += xv*wa.y; l[2] += xv*wa.z; l[3] += xv*wa.w;
        l[4] += xv*wb.x; l[5] += xv*wb.y; l[6] += xv*wb.z; l[7] += xv*wb.w;
    }
#pragma unroll
    for (int e = 0; e < NEXP; ++e) {
#pragma unroll
        for (int s = 32; s > 0; s >>= 1)
            l[e] += __shfl_xor(l[e], s, 64);
    }
    if (lane == 0) {
        int i1 = 0; float b1 = l[0];
#pragma unroll
        for (int e = 1; e < NEXP; ++e) if (l[e] > b1) { b1 = l[e]; i1 = e; }
        int i2 = -1; float b2 = 0.f;
#pragma unroll
        for (int e = 0; e < NEXP; ++e) {
            if (e == i1) continue;
            if (i2 < 0 || l[e] > b2) { b2 = l[e]; i2 = e; }
        }
        float p1 = 1.f / (1.f + __expf(b2 - b1));
        float p2 = 1.f - p1;
        int pos = atomicAdd(&cnt[i1], 1);
        tok[i1*T_TOK + pos] = t;  wt[i1*T_TOK + pos] = p1;
        pos = atomicAdd(&cnt[i2], 1);
        tok[i2*T_TOK + pos] = t;  wt[i2*T_TOK + pos] = p2;
    }
}

// ---------------- compact CAP-spaced bins -> expert-contiguous slots -------------
__global__ void k_compact(const int* __restrict__ cnt,
                          const int* __restrict__ tok, const float* __restrict__ wt,
                          int* __restrict__ ctok, float* __restrict__ cwt)
{
    int e = blockIdx.x;
    int off = 0;
    for (int i = 0; i < e; ++i) off += cnt[i];
    int n = cnt[e];
    for (int i = threadIdx.x; i < n; i += blockDim.x) {
        ctok[off + i] = tok[e*T_TOK + i];
        cwt [off + i] = wt [e*T_TOK + i];
    }
}

// ---------------- fused fp32->bf16 cast + 64x64 transpose ------------------------
#define TS 72
__global__ void k_transpose_cast(const float* __restrict__ in, u16* __restrict__ out,
                                 int R, int C)
{
    __shared__ u16 tle[64*TS];
    size_t mb = (size_t)blockIdx.z * (size_t)R * C;
    int r0 = blockIdx.x * 64, c0 = blockIdx.y * 64;
    int tid = threadIdx.x;
    const float* I = in + mb + (size_t)r0*C + c0;
#pragma unroll
    for (int p = 0; p < 4; ++p) {
        int q = tid + p*256;
        int r = q >> 4, cc = (q & 15) * 4;
        float4 v = *(const float4*)&I[(size_t)r*C + cc];
        tle[(cc+0)*TS + r] = f2b(v.x);
        tle[(cc+1)*TS + r] = f2b(v.y);
        tle[(cc+2)*TS + r] = f2b(v.z);
        tle[(cc+3)*TS + r] = f2b(v.w);
    }
    __syncthreads();
    u16* O = out + mb + (size_t)c0*R + r0;
    int rc = tid & 7, oc = tid >> 3;
#pragma unroll
    for (int p = 0; p < 2; ++p) {
        int c = oc + p*32;
        *(uint4*)&O[(size_t)c*R + rc*8] = *(const uint4*)&tle[c*TS + rc*8];
    }
}

// ---------------- GEMM1: H = silu(Xg@W1) * (Xg@W3) -------------------------------
// BK=64, 2-barrier loop, XOR-swizzled staging (source pre-swizzle, m173 pattern):
// LDS[row][chunk j] holds global chunk j^(row&7); reads XOR back -> uniform banks.
// Tile 128 tok x 64 h (W1 and W3), 2x2 waves, 32 MFMA/wave/phase, 16 phases.
__global__ __launch_bounds__(256, 3) void k_gemm1(
    const u16* __restrict__ X, const u16* __restrict__ W1t, const u16* __restrict__ W3t,
    u16* __restrict__ Hbuf, const int* __restrict__ cnt, const int* __restrict__ ctok)
{
    __shared__ u16 As[128*64];
    __shared__ u16 Bs[128*64];     // rows 0-63: W1 cols, 64-127: W3 cols
    __shared__ int tokLds[128];

    const int bid = blockIdx.x;
    const int e   = bid & 7;
    const int q   = bid >> 3;
    const int mt0 = q & (CAP-1);
    const int col = q >> CAPL;               // 0..43
    const int ne  = cnt[e];
    const int ntile = (ne + 127) >> 7;
    if (mt0 >= ntile) return;
    int off = 0;
    for (int i = 0; i < e; ++i) off += cnt[i];
    const int h0 = col * 64;

    const int tid = threadIdx.x, wave = tid >> 6, lane = tid & 63;
    const int wr = wave >> 1, wc = wave & 1;
    const int quad = lane >> 4, lr = lane & 15;
    const int lrow8 = lane >> 3;
    const int sw = ((lane & 7) ^ lrow8) * 8;   // swizzled source chunk offset (elems)

    const size_t wb = (size_t)e * HID * DIM;
    const u16* Wsel = (wave < 2) ? W1t : W3t;
    const u16* bp[4];
#pragma unroll
    for (int c = 0; c < 4; ++c)
        bp[c] = Wsel + wb + (size_t)(h0 + (wave & 1)*32 + c*8 + lrow8)*DIM + sw;

    for (int tile = mt0; tile < ntile; tile += CAP) {
        const int m0 = tile << 7;
        int nvalid = ne - m0; if (nvalid > 128) nvalid = 128;

        __syncthreads();
        if (tid < 128) {
            int i = (tid < nvalid) ? tid : (nvalid - 1);
            tokLds[tid] = ctok[off + m0 + i];
        }
        __syncthreads();
        const u16* ap[4];
#pragma unroll
        for (int c = 0; c < 4; ++c)
            ap[c] = X + (size_t)tokLds[wave*32 + c*8 + lrow8]*DIM + sw;

        f32x4 a1[4][2], a3[4][2];
#pragma unroll
        for (int m = 0; m < 4; ++m)
#pragma unroll
            for (int n = 0; n < 2; ++n) {
                a1[m][n] = (f32x4){0.f,0.f,0.f,0.f};
                a3[m][n] = (f32x4){0.f,0.f,0.f,0.f};
            }

        for (int k0 = 0; k0 < DIM; k0 += 64) {
            __syncthreads();
#pragma unroll
            for (int c = 0; c < 4; ++c) {
                glds16(ap[c] + k0, &As[(wave*32 + c*8)*64]);
                glds16(bp[c] + k0, &Bs[(wave*32 + c*8)*64]);
            }
            __syncthreads();
#pragma unroll
            for (int kk = 0; kk < 2; ++kk) {
                const int jx = ((kk*4 + quad) ^ (lr & 7)) * 8;
                bf16x8 af[4], b1[2], b3[2];
#pragma unroll
                for (int m = 0; m < 4; ++m)
                    af[m] = *(const bf16x8*)&As[(wr*64 + m*16 + lr)*64 + jx];
#pragma unroll
                for (int n = 0; n < 2; ++n) {
                    b1[n] = *(const bf16x8*)&Bs[(wc*32 + n*16 + lr)*64 + jx];
                    b3[n] = *(const bf16x8*)&Bs[(64 + wc*32 + n*16 + lr)*64 + jx];
                }
#pragma unroll
                for (int m = 0; m < 4; ++m)
#pragma unroll
                    for (int n = 0; n < 2; ++n) {
                        a1[m][n] = __builtin_amdgcn_mfma_f32_16x16x32_bf16(af[m], b1[n], a1[m][n], 0, 0, 0);
                        a3[m][n] = __builtin_amdgcn_mfma_f32_16x16x32_bf16(af[m], b3[n], a3[m][n], 0, 0, 0);
                    }
            }
        }

        // C/D: row = quad*4 + rr, col = lr
#pragma unroll
        for (int m = 0; m < 4; ++m) {
            int mb_ = wr*64 + m*16 + quad*4;
#pragma unroll
            for (int rr = 0; rr < 4; ++rr) {
                int mm = mb_ + rr;
                if (mm >= nvalid) continue;
                u16* hrow = Hbuf + (size_t)(off + m0 + mm)*HID + h0 + wc*32 + lr;
#pragma unroll
                for (int n = 0; n < 2; ++n) {
                    float g = a1[m][n][rr];
                    float u = a3[m][n][rr];
                    hrow[n*16] = f2b((g / (1.f + __expf(-g))) * u);
                }
            }
        }
    }
}

// ---------------- GEMM2: out[t] += w * (H@W2) ------------------------------------
// BK=64, swizzled staging like gemm1. Tile 128 tok x 128 d, K-split 2 (1408),
// 2x2 waves, 32 MFMA/wave/phase, 22 phases per K-slice.
__global__ __launch_bounds__(256, 3) void k_gemm2(
    const u16* __restrict__ Hbuf, const u16* __restrict__ W2t,
    float* __restrict__ outf, const int* __restrict__ cnt,
    const int* __restrict__ ctok, const float* __restrict__ cwt)
{
    __shared__ u16 As[128*64];
    __shared__ u16 Bs[128*64];
    __shared__ int   tLds[128];
    __shared__ float wLds[128];

    const int bid = blockIdx.x;
    const int e   = bid & 7;
    const int q   = bid >> 3;
    const int mt0 = q & (CAP-1);
    const int r2  = q >> CAPL;
    const int zk  = r2 & 1;
    const int d0  = (r2 >> 1) * 128;
    const int ne  = cnt[e];
    const int ntile = (ne + 127) >> 7;
    if (mt0 >= ntile) return;
    int off = 0;
    for (int i = 0; i < e; ++i) off += cnt[i];
    const int kb = zk * (HID/2);             // 1408-elem K slice

    const int tid = threadIdx.x, wave = tid >> 6, lane = tid & 63;
    const int wr = wave >> 1, wc = wave & 1;
    const int quad = lane >> 4, lr = lane & 15;
    const int lrow8 = lane >> 3;
    const int sw = ((lane & 7) ^ lrow8) * 8;

    const size_t w2b = (size_t)e * DIM * HID;
    const u16* bp[4];
#pragma unroll
    for (int c = 0; c < 4; ++c)
        bp[c] = W2t + w2b + (size_t)(d0 + wave*32 + c*8 + lrow8)*HID + kb + sw;

    for (int tile = mt0; tile < ntile; tile += CAP) {
        const int m0 = tile << 7;
        int nvalid = ne - m0; if (nvalid > 128) nvalid = 128;

        __syncthreads();
        if (tid < 128) {
            int i = (tid < nvalid) ? tid : (nvalid - 1);
            tLds[tid] = ctok[off + m0 + i];
            wLds[tid] = cwt [off + m0 + i];
        }
        __syncthreads();
        const u16* ap[4];
#pragma unroll
        for (int c = 0; c < 4; ++c) {
            int r = wave*32 + c*8 + lrow8;
            if (r >= nvalid) r = nvalid - 1;
            ap[c] = Hbuf + (size_t)(off + m0 + r)*HID + kb + sw;
        }

        f32x4 acc[4][4];
#pragma unroll
        for (int a = 0; a < 4; ++a)
#pragma unroll
            for (int b = 0; b < 4; ++b) acc[a][b] = (f32x4){0.f,0.f,0.f,0.f};

        for (int k0 = 0; k0 < HID/2; k0 += 64) {
            __syncthreads();
#pragma unroll
            for (int c = 0; c < 4; ++c) {
                glds16(ap[c] + k0, &As[(wave*32 + c*8)*64]);
                glds16(bp[c] + k0, &Bs[(wave*32 + c*8)*64]);
            }
            __syncthreads();
#pragma unroll
            for (int kk = 0; kk < 2; ++kk) {
                const int jx = ((kk*4 + quad) ^ (lr & 7)) * 8;
                bf16x8 af[4], bf[4];
#pragma unroll
                for (int m = 0; m < 4; ++m)
                    af[m] = *(const bf16x8*)&As[(wr*64 + m*16 + lr)*64 + jx];
#pragma unroll
                for (int n = 0; n < 4; ++n)
                    bf[n] = *(const bf16x8*)&Bs[(wc*64 + n*16 + lr)*64 + jx];
#pragma unroll
                for (int m = 0; m < 4; ++m)
#pragma unroll
                    for (int n = 0; n < 4; ++n)
                        acc[m][n] = __builtin_amdgcn_mfma_f32_16x16x32_bf16(af[m], bf[n], acc[m][n], 0, 0, 0);
            }
        }

#pragma unroll
        for (int m = 0; m < 4; ++m) {
            int mb_ = wr*64 + m*16 + quad*4;
#pragma unroll
            for (int rr = 0; rr < 4; ++rr) {
                int mm = mb_ + rr;
                if (mm >= nvalid) continue;
                float wr_ = wLds[mm];
                float* orow = outf + (size_t)tLds[mm]*DIM + d0 + wc*64 + lr;
#pragma unroll
                for (int n = 0; n < 4; ++n)
                    atomicAdd(&orow[n*16], acc[m][n][rr] * wr_);
            }
        }
    }
}

extern "C" void kernel_launch(void* const* d_in, const int* in_sizes, int n_in,
                              void* d_out, int out_size, void* d_ws, size_t ws_size,
                              hipStream_t stream)
{
    const float* x  = (const float*)d_in[0];
    const float* wg = (const float*)d_in[1];
    const float* w1 = (const float*)d_in[2];
    const float* w2 = (const float*)d_in[3];
    const float* w3 = (const float*)d_in[4];
    float* outf = (float*)d_out;

    char* ws = (char*)d_ws;
    int*   cnt  = (int*)  (ws);                       //        256 B
    int*   tok  = (int*)  (ws + 256);                 //    131,072
    float* wt   = (float*)(ws + 131328);              //    131,072
    int*   ctok = (int*)  (ws + 262400);              //     32,768
    float* cwt  = (float*)(ws + 295168);              //     32,768
    u16*   Xbf  = (u16*)  (ws + 327936);              //  8,388,608
    u16*   Hbuf = (u16*)  (ws + 8716544);             // 46,137,344
    u16*   W1t  = (u16*)  (ws + 54853888);            // 46,137,344
    u16*   W3t  = (u16*)  (ws + 100991232);           // 46,137,344
    u16*   W2t  = (u16*)  (ws + 147128576);           // 46,137,344 -> 193,265,920 total

    hipMemsetAsync(cnt, 0, 256, stream);
    hipMemsetAsync(outf, 0, (size_t)T_TOK*DIM*sizeof(float), stream);

    k_transpose_cast<<<dim3(DIM/64, HID/64, NEXP), 256, 0, stream>>>(w1, W1t, DIM, HID);
    k_transpose_cast<<<dim3(DIM/64, HID/64, NEXP), 256, 0, stream>>>(w3, W3t, DIM, HID);
    k_transpose_cast<<<dim3(HID/64, DIM/64, NEXP), 256, 0, stream>>>(w2, W2t, HID, DIM);

    k_gating<<<T_TOK/4, 256, 0, stream>>>(x, wg, cnt, tok, wt, Xbf);
    k_compact<<<NEXP, 256, 0, stream>>>(cnt, tok, wt, ctok, cwt);

    k_gemm1<<<NEXP*(HID/64)*CAP, 256, 0, stream>>>(Xbf, W1t, W3t, Hbuf, cnt, ctok);
    k_gemm2<<<NEXP*CAP*2*(DIM/128), 256, 0, stream>>>(Hbuf, W2t, outf, cnt, ctok, cwt);
}

// Round 3
// 663.129 us; speedup vs baseline: 1.1076x; 1.1076x over previous
//
#include <hip/hip_runtime.h>
#include <hip/hip_bf16.h>

typedef unsigned short u16;
typedef __bf16 bf16_t;
typedef bf16_t bf16x8 __attribute__((ext_vector_type(8)));
typedef float f32x4 __attribute__((ext_vector_type(4)));

#define T_TOK 4096
#define DIM   1024
#define NEXP  8
#define HID   2816
#define CAP   16

static __device__ __forceinline__ u16 f2b(float f) {
    __hip_bfloat16 h = __float2bfloat16(f);
    return *(u16*)&h;
}

// async global->LDS: HW writes lane i's 16B at (wave-uniform base)+i*16
static __device__ __forceinline__ void glds16(const u16* g, u16* l) {
    __builtin_amdgcn_global_load_lds((const __attribute__((address_space(1))) void*)g,
                                     (__attribute__((address_space(3))) void*)l, 16, 0, 0);
}

// ---------------- gating (+ fused fp32->bf16 X cast) -----------------------------
__global__ void k_gating(const float* __restrict__ X,
                         const float* __restrict__ WG,
                         int* __restrict__ cnt,
                         int* __restrict__ tok,
                         float* __restrict__ wt,
                         u16* __restrict__ Xbf)
{
    int wv   = threadIdx.x >> 6;
    int lane = threadIdx.x & 63;
    int t = blockIdx.x * 4 + wv;
    float l[NEXP];
#pragma unroll
    for (int e = 0; e < NEXP; ++e) l[e] = 0.f;
#pragma unroll
    for (int i = 0; i < DIM/64; ++i) {
        int d = i*64 + lane;
        float xv = X[(size_t)t*DIM + d];
        Xbf[(size_t)t*DIM + d] = f2b(xv);
        const float* wrow = WG + (size_t)d*NEXP;
        float4 wa = *(const float4*)wrow;
        float4 wb = *(const float4*)(wrow + 4);
        l[0] += xv*wa.x; l[1] += xv*wa.y; l[2] += xv*wa.z; l[3] += xv*wa.w;
        l[4] += xv*wb.x; l[5] += xv*wb.y; l[6] += xv*wb.z; l[7] += xv*wb.w;
    }
#pragma unroll
    for (int e = 0; e < NEXP; ++e) {
#pragma unroll
        for (int s = 32; s > 0; s >>= 1)
            l[e] += __shfl_xor(l[e], s, 64);
    }
    if (lane == 0) {
        int i1 = 0; float b1 = l[0];
#pragma unroll
        for (int e = 1; e < NEXP; ++e) if (l[e] > b1) { b1 = l[e]; i1 = e; }
        int i2 = -1; float b2 = 0.f;
#pragma unroll
        for (int e = 0; e < NEXP; ++e) {
            if (e == i1) continue;
            if (i2 < 0 || l[e] > b2) { b2 = l[e]; i2 = e; }
        }
        float p1 = 1.f / (1.f + __expf(b2 - b1));
        float p2 = 1.f - p1;
        int pos = atomicAdd(&cnt[i1], 1);
        tok[i1*T_TOK + pos] = t;  wt[i1*T_TOK + pos] = p1;
        pos = atomicAdd(&cnt[i2], 1);
        tok[i2*T_TOK + pos] = t;  wt[i2*T_TOK + pos] = p2;
    }
}

// ---------------- compact CAP-spaced bins -> expert-contiguous slots -------------
__global__ void k_compact(const int* __restrict__ cnt,
                          const int* __restrict__ tok, const float* __restrict__ wt,
                          int* __restrict__ ctok, float* __restrict__ cwt)
{
    int e = blockIdx.x;
    int off = 0;
    for (int i = 0; i < e; ++i) off += cnt[i];
    int n = cnt[e];
    for (int i = threadIdx.x; i < n; i += blockDim.x) {
        ctok[off + i] = tok[e*T_TOK + i];
        cwt [off + i] = wt [e*T_TOK + i];
    }
}

// ---------------- fused fp32->bf16 cast + 64x64 transpose ------------------------
#define TS 72
__global__ void k_transpose_cast(const float* __restrict__ in, u16* __restrict__ out,
                                 int R, int C)
{
    __shared__ u16 tle[64*TS];
    size_t mb = (size_t)blockIdx.z * (size_t)R * C;
    int r0 = blockIdx.x * 64, c0 = blockIdx.y * 64;
    int tid = threadIdx.x;
    const float* I = in + mb + (size_t)r0*C + c0;
#pragma unroll
    for (int p = 0; p < 4; ++p) {
        int q = tid + p*256;
        int r = q >> 4, cc = (q & 15) * 4;
        float4 v = *(const float4*)&I[(size_t)r*C + cc];
        tle[(cc+0)*TS + r] = f2b(v.x);
        tle[(cc+1)*TS + r] = f2b(v.y);
        tle[(cc+2)*TS + r] = f2b(v.z);
        tle[(cc+3)*TS + r] = f2b(v.w);
    }
    __syncthreads();
    u16* O = out + mb + (size_t)c0*R + r0;
    int rc = tid & 7, oc = tid >> 3;
#pragma unroll
    for (int p = 0; p < 2; ++p) {
        int c = oc + p*32;
        *(uint4*)&O[(size_t)c*R + rc*8] = *(const uint4*)&tle[c*TS + rc*8];
    }
}

// ---------------- GEMM1: H = silu(Xg@W1) * (Xg@W3) -------------------------------
// BK=32 (round-0 structure) + XOR-swizzled chunks:
// LDS[row][chunk'] holds global chunk chunk'^((row>>1)&3); octet-distinct 16B
// slots on ds_read_b128 (validated zero-conflict model from round 2).
// Tile 128 tok x 64 h, 2x2 waves, 16 MFMA/wave/iter.
__global__ __launch_bounds__(256, 3) void k_gemm1(
    const u16* __restrict__ X, const u16* __restrict__ W1t, const u16* __restrict__ W3t,
    u16* __restrict__ Hbuf, const int* __restrict__ cnt, const int* __restrict__ ctok)
{
    __shared__ u16 As[128*32];
    __shared__ u16 Bs[128*32];     // rows 0-63: W1 cols, 64-127: W3 cols
    __shared__ int tokLds[128];

    const int bid = blockIdx.x;
    const int e   = bid & 7;
    const int q   = bid >> 3;
    const int mt0 = q & (CAP-1);
    const int col = q >> 4;                  // 0..43
    const int ne  = cnt[e];
    const int ntile = (ne + 127) >> 7;
    if (mt0 >= ntile) return;
    int off = 0;
    for (int i = 0; i < e; ++i) off += cnt[i];
    const int h0 = col * 64;

    const int tid = threadIdx.x, wave = tid >> 6, lane = tid & 63;
    const int wr = wave >> 1, wc = wave & 1;
    const int quad = lane >> 4, lr = lane & 15;
    const int lrow = lane >> 2;
    const int swk  = ((lane & 3) ^ ((lane >> 3) & 3)) * 8;   // swizzled src chunk
    const int jx   = (quad ^ ((lr >> 1) & 3)) * 8;           // swizzled read chunk

    const size_t wb = (size_t)e * HID * DIM;
    const u16* w1g = W1t + wb + (size_t)(h0 + wave*16 + lrow)*DIM + swk;
    const u16* w3g = W3t + wb + (size_t)(h0 + wave*16 + lrow)*DIM + swk;
    u16* aL0 = &As[(wave*16)*32];
    u16* aL1 = &As[(64 + wave*16)*32];
    u16* bL0 = &Bs[(wave*16)*32];
    u16* bL1 = &Bs[(64 + wave*16)*32];

    for (int tile = mt0; tile < ntile; tile += CAP) {
        const int m0 = tile << 7;
        int nvalid = ne - m0; if (nvalid > 128) nvalid = 128;

        __syncthreads();
        if (tid < 128) {
            int i = (tid < nvalid) ? tid : (nvalid - 1);
            tokLds[tid] = ctok[off + m0 + i];
        }
        __syncthreads();
        const u16* ag0 = X + (size_t)tokLds[wave*16 + lrow]*DIM + swk;
        const u16* ag1 = X + (size_t)tokLds[64 + wave*16 + lrow]*DIM + swk;

        f32x4 a1[4][2], a3[4][2];
#pragma unroll
        for (int m = 0; m < 4; ++m)
#pragma unroll
            for (int n = 0; n < 2; ++n) {
                a1[m][n] = (f32x4){0.f,0.f,0.f,0.f};
                a3[m][n] = (f32x4){0.f,0.f,0.f,0.f};
            }

        for (int k0 = 0; k0 < DIM; k0 += 32) {
            __syncthreads();
            glds16(ag0 + k0, aL0);
            glds16(ag1 + k0, aL1);
            glds16(w1g + k0, bL0);
            glds16(w3g + k0, bL1);
            __syncthreads();
            bf16x8 af[4], b1[2], b3[2];
#pragma unroll
            for (int m = 0; m < 4; ++m)
                af[m] = *(const bf16x8*)&As[(wr*64 + m*16 + lr)*32 + jx];
#pragma unroll
            for (int n = 0; n < 2; ++n) {
                b1[n] = *(const bf16x8*)&Bs[(wc*32 + n*16 + lr)*32 + jx];
                b3[n] = *(const bf16x8*)&Bs[(64 + wc*32 + n*16 + lr)*32 + jx];
            }
#pragma unroll
            for (int m = 0; m < 4; ++m)
#pragma unroll
                for (int n = 0; n < 2; ++n) {
                    a1[m][n] = __builtin_amdgcn_mfma_f32_16x16x32_bf16(af[m], b1[n], a1[m][n], 0, 0, 0);
                    a3[m][n] = __builtin_amdgcn_mfma_f32_16x16x32_bf16(af[m], b3[n], a3[m][n], 0, 0, 0);
                }
        }

        // C/D: row = quad*4 + rr, col = lr
#pragma unroll
        for (int m = 0; m < 4; ++m) {
            int mb_ = wr*64 + m*16 + quad*4;
#pragma unroll
            for (int rr = 0; rr < 4; ++rr) {
                int mm = mb_ + rr;
                if (mm >= nvalid) continue;
                u16* hrow = Hbuf + (size_t)(off + m0 + mm)*HID + h0 + wc*32 + lr;
#pragma unroll
                for (int n = 0; n < 2; ++n) {
                    float g = a1[m][n][rr];
                    float u = a3[m][n][rr];
                    hrow[n*16] = f2b((g / (1.f + __expf(-g))) * u);
                }
            }
        }
    }
}

// ---------------- GEMM2: out[t] += w * (H@W2) ------------------------------------
// BK=32 (round-0 structure) + same XOR swizzle. Tile 128 tok x 128 d, K-split 2.
__global__ __launch_bounds__(256, 3) void k_gemm2(
    const u16* __restrict__ Hbuf, const u16* __restrict__ W2t,
    float* __restrict__ outf, const int* __restrict__ cnt,
    const int* __restrict__ ctok, const float* __restrict__ cwt)
{
    __shared__ u16 As[128*32];
    __shared__ u16 Bs[128*32];
    __shared__ int   tLds[128];
    __shared__ float wLds[128];

    const int bid = blockIdx.x;
    const int e   = bid & 7;
    const int q   = bid >> 3;
    const int mt0 = q & (CAP-1);
    const int r2  = q >> 4;
    const int zk  = r2 & 1;
    const int d0  = (r2 >> 1) * 128;
    const int ne  = cnt[e];
    const int ntile = (ne + 127) >> 7;
    if (mt0 >= ntile) return;
    int off = 0;
    for (int i = 0; i < e; ++i) off += cnt[i];
    const int kb = zk * (HID/2);             // 1408-elem K slice

    const int tid = threadIdx.x, wave = tid >> 6, lane = tid & 63;
    const int wr = wave >> 1, wc = wave & 1;
    const int quad = lane >> 4, lr = lane & 15;
    const int lrow = lane >> 2;
    const int swk  = ((lane & 3) ^ ((lane >> 3) & 3)) * 8;
    const int jx   = (quad ^ ((lr >> 1) & 3)) * 8;

    const size_t w2b = (size_t)e * DIM * HID;
    const u16* bg0 = W2t + w2b + (size_t)(d0 + wave*16 + lrow)*HID + kb + swk;
    const u16* bg1 = bg0 + (size_t)64*HID;
    u16* aL0 = &As[(wave*16)*32];
    u16* aL1 = &As[(64 + wave*16)*32];
    u16* bL0 = &Bs[(wave*16)*32];
    u16* bL1 = &Bs[(64 + wave*16)*32];

    for (int tile = mt0; tile < ntile; tile += CAP) {
        const int m0 = tile << 7;
        int nvalid = ne - m0; if (nvalid > 128) nvalid = 128;

        __syncthreads();
        if (tid < 128) {
            int i = (tid < nvalid) ? tid : (nvalid - 1);
            tLds[tid] = ctok[off + m0 + i];
            wLds[tid] = cwt [off + m0 + i];
        }
        __syncthreads();
        int ar0 = wave*16 + lrow;      if (ar0 >= nvalid) ar0 = nvalid - 1;
        int ar1 = 64 + wave*16 + lrow; if (ar1 >= nvalid) ar1 = nvalid - 1;
        const u16* ag0 = Hbuf + (size_t)(off + m0 + ar0)*HID + kb + swk;
        const u16* ag1 = Hbuf + (size_t)(off + m0 + ar1)*HID + kb + swk;

        f32x4 acc[4][4];
#pragma unroll
        for (int a = 0; a < 4; ++a)
#pragma unroll
            for (int b = 0; b < 4; ++b) acc[a][b] = (f32x4){0.f,0.f,0.f,0.f};

        for (int k0 = 0; k0 < HID/2; k0 += 32) {
            __syncthreads();
            glds16(ag0 + k0, aL0);
            glds16(ag1 + k0, aL1);
            glds16(bg0 + k0, bL0);
            glds16(bg1 + k0, bL1);
            __syncthreads();
            bf16x8 af[4], bf[4];
#pragma unroll
            for (int m = 0; m < 4; ++m)
                af[m] = *(const bf16x8*)&As[(wr*64 + m*16 + lr)*32 + jx];
#pragma unroll
            for (int n = 0; n < 4; ++n)
                bf[n] = *(const bf16x8*)&Bs[(wc*64 + n*16 + lr)*32 + jx];
#pragma unroll
            for (int m = 0; m < 4; ++m)
#pragma unroll
                for (int n = 0; n < 4; ++n)
                    acc[m][n] = __builtin_amdgcn_mfma_f32_16x16x32_bf16(af[m], bf[n], acc[m][n], 0, 0, 0);
        }

#pragma unroll
        for (int m = 0; m < 4; ++m) {
            int mb_ = wr*64 + m*16 + quad*4;
#pragma unroll
            for (int rr = 0; rr < 4; ++rr) {
                int mm = mb_ + rr;
                if (mm >= nvalid) continue;
                float wr_ = wLds[mm];
                float* orow = outf + (size_t)tLds[mm]*DIM + d0 + wc*64 + lr;
#pragma unroll
                for (int n = 0; n < 4; ++n)
                    atomicAdd(&orow[n*16], acc[m][n][rr] * wr_);
            }
        }
    }
}

extern "C" void kernel_launch(void* const* d_in, const int* in_sizes, int n_in,
                              void* d_out, int out_size, void* d_ws, size_t ws_size,
                              hipStream_t stream)
{
    const float* x  = (const float*)d_in[0];
    const float* wg = (const float*)d_in[1];
    const float* w1 = (const float*)d_in[2];
    const float* w2 = (const float*)d_in[3];
    const float* w3 = (const float*)d_in[4];
    float* outf = (float*)d_out;

    char* ws = (char*)d_ws;
    int*   cnt  = (int*)  (ws);                       //        256 B
    int*   tok  = (int*)  (ws + 256);                 //    131,072
    float* wt   = (float*)(ws + 131328);              //    131,072
    int*   ctok = (int*)  (ws + 262400);              //     32,768
    float* cwt  = (float*)(ws + 295168);              //     32,768
    u16*   Xbf  = (u16*)  (ws + 327936);              //  8,388,608
    u16*   Hbuf = (u16*)  (ws + 8716544);             // 46,137,344
    u16*   W1t  = (u16*)  (ws + 54853888);            // 46,137,344
    u16*   W3t  = (u16*)  (ws + 100991232);           // 46,137,344
    u16*   W2t  = (u16*)  (ws + 147128576);           // 46,137,344 -> 193,265,920 total

    hipMemsetAsync(cnt, 0, 256, stream);
    hipMemsetAsync(outf, 0, (size_t)T_TOK*DIM*sizeof(float), stream);

    k_transpose_cast<<<dim3(DIM/64, HID/64, NEXP), 256, 0, stream>>>(w1, W1t, DIM, HID);
    k_transpose_cast<<<dim3(DIM/64, HID/64, NEXP), 256, 0, stream>>>(w3, W3t, DIM, HID);
    k_transpose_cast<<<dim3(HID/64, DIM/64, NEXP), 256, 0, stream>>>(w2, W2t, HID, DIM);

    k_gating<<<T_TOK/4, 256, 0, stream>>>(x, wg, cnt, tok, wt, Xbf);
    k_compact<<<NEXP, 256, 0, stream>>>(cnt, tok, wt, ctok, cwt);

    k_gemm1<<<NEXP*(HID/64)*CAP, 256, 0, stream>>>(Xbf, W1t, W3t, Hbuf, cnt, ctok);
    k_gemm2<<<NEXP*CAP*2*(DIM/128), 256, 0, stream>>>(Hbuf, W2t, outf, cnt, ctok, cwt);
}